// Round 5
// baseline (229.769 us; speedup 1.0000x reference)
//
#include <hip/hip_runtime.h>
#include <math.h>

#define Cc 32
#define CH 16                 // channels per half-block
#define Hc 128
#define Wc 160
#define Dc 48
#define HWc (Hc*Wc)
#define TS 16
#define HALO (TS+2)           // 18
#define NPOS (HALO*HALO)      // 324
#define DCHUNK 8
#define NCHUNK (Dc/DCHUNK)    // 6
#define VSTR4 5               // var row stride in float4 (20 floats = 80B, pads 16ch)
#define PSTR4 3               // param stride in float4 (cw0, cw1, ci-pack)
#define NPASS 6               // ceil(NPOS*4 / 256)

// ---------------- kernel 1: projection matrices + weight repack ----------------
__global__ void k_proj(const float* __restrict__ proj, const float* __restrict__ wreg,
                       float* __restrict__ wsproj, float* __restrict__ w2) {
    const int tid = threadIdx.x;
    for (int i = tid; i < 2 * 9 * 3 * CH; i += 64) {
        int c = i & 15;
        int t = i >> 4;          // (half*9+khkw)*3 + kd
        int kd = t % 3;
        int t2 = t / 3;          // half*9 + khkw
        int khkw = t2 % 9;
        int half = t2 / 9;
        int ch = half * CH + c;
        w2[i] = wreg[ch * 27 + kd * 9 + khkw];
    }
    if (tid != 0) return;
    float a[4][8];
    for (int i = 0; i < 4; i++)
        for (int j = 0; j < 4; j++) {
            a[i][j]     = proj[i * 4 + j];
            a[i][j + 4] = (i == j) ? 1.f : 0.f;
        }
    for (int col = 0; col < 4; col++) {
        int piv = col; float best = fabsf(a[col][col]);
        for (int r = col + 1; r < 4; r++) {
            float v = fabsf(a[r][col]);
            if (v > best) { best = v; piv = r; }
        }
        if (piv != col)
            for (int j = 0; j < 8; j++) { float t = a[col][j]; a[col][j] = a[piv][j]; a[piv][j] = t; }
        float inv = 1.f / a[col][col];
        for (int j = 0; j < 8; j++) a[col][j] *= inv;
        for (int r = 0; r < 4; r++) if (r != col) {
            float f = a[r][col];
            for (int j = 0; j < 8; j++) a[r][j] -= f * a[col][j];
        }
    }
    for (int v = 1; v < 3; v++) {
        const float* P = proj + v * 16;
        float M[3][4];
        for (int i = 0; i < 3; i++)
            for (int j = 0; j < 4; j++) {
                float s = 0.f;
                for (int k = 0; k < 4; k++) s += P[i * 4 + k] * a[k][4 + j];
                M[i][j] = s;
            }
        float* o = wsproj + (v - 1) * 12;
        o[0] = M[0][0]; o[1] = M[0][1]; o[2] = M[0][2];
        o[3] = M[1][0]; o[4] = M[1][1]; o[5] = M[1][2];
        o[6] = M[2][0]; o[7] = M[2][1]; o[8] = M[2][2];
        o[9] = M[0][3]; o[10] = M[1][3]; o[11] = M[2][3];
    }
}

// ---------------- kernel 1b: CHW -> HWC transpose of the 3 feature maps ----------------
__global__ void k_transpose(const float* __restrict__ f0, const float* __restrict__ f1,
                            const float* __restrict__ f2, float* __restrict__ o0,
                            float* __restrict__ o1, float* __restrict__ o2) {
    const int p = blockIdx.x * 256 + threadIdx.x;   // pixel
    if (p >= HWc) return;
    const float* f = (blockIdx.y == 0) ? f0 : (blockIdx.y == 1) ? f1 : f2;
    float*       o = (blockIdx.y == 0) ? o0 : (blockIdx.y == 1) ? o1 : o2;
    float v[Cc];
#pragma unroll
    for (int c = 0; c < Cc; c++) v[c] = f[c * HWc + p];   // coalesced across lanes
    float4* o4 = (float4*)(o + (size_t)p * Cc);
#pragma unroll
    for (int j = 0; j < 8; j++)
        o4[j] = make_float4(v[4 * j], v[4 * j + 1], v[4 * j + 2], v[4 * j + 3]);
}

// ---------------- kernel 2: fused warp + variance + 3D conv (per channel half) ----------------
// launch_bounds (256,2): 128-VGPR cap. (256,4)=64-VGPR cap caused massive scratch
// spills (679MB WRITE_SIZE, R2). Guard metric: WRITE_SIZE ~7.7MB == no spills.
// R5: producer/consumer split. Phase A (1 thread : 1 halo position) computes
// homography+bilinear params once per (position,depth) and stores packed in LDS;
// Phase B (quads, cc=tid&3) does the coalesced gathers + variance using the
// shared params (R4 replicated the warp math 4x across each quad -> VALU-bound).
// Phase A for slice d+1 runs inside the conv phase of slice d (single param
// buffer is race-free: writes and reads are separated by the two barriers).
__global__ __launch_bounds__(256, 2) void k_cost(
    const float* __restrict__ fT0, const float* __restrict__ fT1, const float* __restrict__ fT2,
    const float* __restrict__ dvals, const float4* __restrict__ w2_4,
    const float* __restrict__ wsproj, float* __restrict__ costA, float* __restrict__ costB)
{
    __shared__ float4 var_l[NPOS * VSTR4];   // 25920 B
    __shared__ float4 par_l[NPOS * PSTR4];   // 15552 B
    __shared__ float projl[24];

    const int tid = threadIdx.x;
    if (tid < 24) projl[tid] = wsproj[tid];
    __syncthreads();

    const int tileX = blockIdx.x;                 // 0..9
    const int tileY = blockIdx.y;                 // 0..7
    const int half  = blockIdx.z & 1;             // channel half
    const int d0    = (blockIdx.z >> 1) * DCHUNK;
    const int tx = tid & 15, ty = tid >> 4;
    const int baseH = tileY * TS - 1, baseW = tileX * TS - 1;

    const int posq = tid >> 2;                    // quad id: position within pass
    const int cc   = tid & 3;                     // float4 slot within half-record
    const int co   = half * 4 + cc;               // float4 offset into 32-ch record

    const float4* fT0_4 = (const float4*)fT0;
    const float4* fT1_4 = (const float4*)fT1;
    const float4* fT2_4 = (const float4*)fT2;

    // ---- Phase A setup: this thread owns positions tid, tid+256; rays hoisted ----
    float rAx[2][2], rAy[2][2], rAz[2][2];
    float trn[2][3];
#pragma unroll
    for (int v = 0; v < 2; v++) {
        trn[v][0] = projl[v * 12 + 9];
        trn[v][1] = projl[v * 12 + 10];
        trn[v][2] = projl[v * 12 + 11];
    }
    int amask = 0;
#pragma unroll
    for (int s = 0; s < 2; s++) {
        int p = tid + s * 256;
        bool act = p < NPOS;
        int pp = act ? p : 0;
        int py = pp / HALO, px = pp % HALO;
        int hyi = baseH + py, hxi = baseW + px;
        bool ok = act && hyi >= 0 && hyi < Hc && hxi >= 0 && hxi < Wc;
        if (ok) amask |= (1 << s);
        float hx = (float)hxi, hy = (float)hyi;
#pragma unroll
        for (int v = 0; v < 2; v++) {
            const float* R = projl + v * 12;
            rAx[s][v] = fmaf(R[0], hx, fmaf(R[1], hy, R[2]));
            rAy[s][v] = fmaf(R[3], hx, fmaf(R[4], hy, R[5]));
            rAz[s][v] = fmaf(R[6], hx, fmaf(R[7], hy, R[8]));
        }
    }

    // ---- Phase B setup: validity + ref pixel index per pass ----
    int   ridxB[NPASS];
    int   bmask = 0;
#pragma unroll
    for (int s = 0; s < NPASS; s++) {
        int p = posq + s * 64;
        bool act = p < NPOS;
        int pp = act ? p : 0;
        int py = pp / HALO, px = pp % HALO;
        int hyi = baseH + py, hxi = baseW + px;
        bool ok = act && hyi >= 0 && hyi < Hc && hxi >= 0 && hxi < Wc;
        if (ok) bmask |= (1 << s);
        ridxB[s] = ok ? (hyi * Wc + hxi) : 0;
    }

    float cost[DCHUNK];
#pragma unroll
    for (int i = 0; i < DCHUNK; i++) cost[i] = 0.f;

    const int convbase = (ty * HALO + tx) * VSTR4;   // float4 index of (ty,tx)

    // ---- Phase A: compute params for slice dpn into par_l ----
    auto phaseA = [&](int dpn) {
        const float depthN = dvals[dpn];
#pragma unroll
        for (int s = 0; s < 2; s++) {
            int p = tid + s * 256;
            if (p >= NPOS) break;
            if (!((amask >> s) & 1)) continue;
            float cw[2][4]; unsigned int pk[4];
#pragma unroll
            for (int v = 0; v < 2; v++) {
                float X = fmaf(rAx[s][v], depthN, trn[v][0]);
                float Y = fmaf(rAy[s][v], depthN, trn[v][1]);
                float Z = fmaf(rAz[s][v], depthN, trn[v][2]);
                float iz = 1.f / Z;
                float gx = X * iz, gy = Y * iz;
                float x0f = floorf(gx), y0f = floorf(gy);
                float wx = gx - x0f, wy = gy - y0f;
                int x0 = (int)x0f, y0 = (int)y0f;
                bool vx0 = (x0 >= 0) & (x0 <= Wc - 1);
                bool vx1 = (x0 + 1 >= 0) & (x0 + 1 <= Wc - 1);
                bool vy0 = (y0 >= 0) & (y0 <= Hc - 1);
                bool vy1 = (y0 + 1 >= 0) & (y0 + 1 <= Hc - 1);
                int xc0 = min(max(x0, 0), Wc - 1), xc1 = min(max(x0 + 1, 0), Wc - 1);
                int yc0 = min(max(y0, 0), Hc - 1), yc1 = min(max(y0 + 1, 0), Hc - 1);
                float ax = 1.f - wx, ay = 1.f - wy;
                cw[v][0] = (vx0 && vy0) ? ax * ay : 0.f;
                cw[v][1] = (vx1 && vy0) ? wx * ay : 0.f;
                cw[v][2] = (vx0 && vy1) ? ax * wy : 0.f;
                cw[v][3] = (vx1 && vy1) ? wx * wy : 0.f;
                unsigned int i0 = (unsigned int)(yc0 * Wc + xc0);
                unsigned int i1 = (unsigned int)(yc0 * Wc + xc1);
                unsigned int i2 = (unsigned int)(yc1 * Wc + xc0);
                unsigned int i3 = (unsigned int)(yc1 * Wc + xc1);
                pk[v * 2 + 0] = i0 | (i1 << 16);
                pk[v * 2 + 1] = i2 | (i3 << 16);
            }
            par_l[p * PSTR4 + 0] = make_float4(cw[0][0], cw[0][1], cw[0][2], cw[0][3]);
            par_l[p * PSTR4 + 1] = make_float4(cw[1][0], cw[1][1], cw[1][2], cw[1][3]);
            par_l[p * PSTR4 + 2] = make_float4(__uint_as_float(pk[0]), __uint_as_float(pk[1]),
                                               __uint_as_float(pk[2]), __uint_as_float(pk[3]));
        }
    };

    const int dpFirst = (d0 == 0) ? 0 : d0 - 1;
    const int dpLast  = min(d0 + DCHUNK, Dc - 1);

    phaseA(dpFirst);
    __syncthreads();

    for (int dp = dpFirst; dp <= dpLast; dp++) {
        // ---- Phase B: gather + variance into var_l using shared params ----
#pragma unroll
        for (int s = 0; s < NPASS; s++) {
            int p = posq + s * 64;
            if (p >= NPOS) continue;                 // only pass 5, posq>=4
            const int vaddr = p * VSTR4 + cc;
            if (!((bmask >> s) & 1)) {
                var_l[vaddr] = make_float4(0.f, 0.f, 0.f, 0.f);
                continue;
            }
            float4 c0 = par_l[p * PSTR4 + 0];        // quad-broadcast reads
            float4 c1 = par_l[p * PSTR4 + 1];
            float4 pkf = par_l[p * PSTR4 + 2];
            unsigned int u0 = __float_as_uint(pkf.x), u1 = __float_as_uint(pkf.y);
            unsigned int u2 = __float_as_uint(pkf.z), u3 = __float_as_uint(pkf.w);
            int i00 = u0 & 0xffff, i01 = u0 >> 16, i02 = u1 & 0xffff, i03 = u1 >> 16;
            int i10 = u2 & 0xffff, i11 = u2 >> 16, i12 = u3 & 0xffff, i13 = u3 >> 16;
            float4 rf  = fT0_4[ridxB[s] * 8 + co];
            float4 t00 = fT1_4[i00 * 8 + co];
            float4 t01 = fT1_4[i01 * 8 + co];
            float4 t10 = fT1_4[i02 * 8 + co];
            float4 t11 = fT1_4[i03 * 8 + co];
            float4 u00 = fT2_4[i10 * 8 + co];
            float4 u01 = fT2_4[i11 * 8 + co];
            float4 u10 = fT2_4[i12 * 8 + co];
            float4 u11 = fT2_4[i13 * 8 + co];
            float4 a1, a2, vr;
            a1.x = fmaf(c0.x, t00.x, fmaf(c0.y, t01.x, fmaf(c0.z, t10.x, c0.w * t11.x)));
            a1.y = fmaf(c0.x, t00.y, fmaf(c0.y, t01.y, fmaf(c0.z, t10.y, c0.w * t11.y)));
            a1.z = fmaf(c0.x, t00.z, fmaf(c0.y, t01.z, fmaf(c0.z, t10.z, c0.w * t11.z)));
            a1.w = fmaf(c0.x, t00.w, fmaf(c0.y, t01.w, fmaf(c0.z, t10.w, c0.w * t11.w)));
            a2.x = fmaf(c1.x, u00.x, fmaf(c1.y, u01.x, fmaf(c1.z, u10.x, c1.w * u11.x)));
            a2.y = fmaf(c1.x, u00.y, fmaf(c1.y, u01.y, fmaf(c1.z, u10.y, c1.w * u11.y)));
            a2.z = fmaf(c1.x, u00.z, fmaf(c1.y, u01.z, fmaf(c1.z, u10.z, c1.w * u11.z)));
            a2.w = fmaf(c1.x, u00.w, fmaf(c1.y, u01.w, fmaf(c1.z, u10.w, c1.w * u11.w)));
            float smx = rf.x + a1.x + a2.x, sqx = fmaf(a2.x, a2.x, fmaf(a1.x, a1.x, rf.x * rf.x));
            float smy = rf.y + a1.y + a2.y, sqy = fmaf(a2.y, a2.y, fmaf(a1.y, a1.y, rf.y * rf.y));
            float smz = rf.z + a1.z + a2.z, sqz = fmaf(a2.z, a2.z, fmaf(a1.z, a1.z, rf.z * rf.z));
            float smw = rf.w + a1.w + a2.w, sqw = fmaf(a2.w, a2.w, fmaf(a1.w, a1.w, rf.w * rf.w));
            vr.x = sqx * (1.f / 3.f) - smx * smx * (1.f / 9.f);
            vr.y = sqy * (1.f / 3.f) - smy * smy * (1.f / 9.f);
            vr.z = sqz * (1.f / 3.f) - smz * smz * (1.f / 9.f);
            vr.w = sqw * (1.f / 3.f) - smw * smw * (1.f / 9.f);
            var_l[vaddr] = vr;
        }
        __syncthreads();

        // ---- Phase A for next slice (overlaps conv latency) ----
        if (dp < dpLast) phaseA(dp + 1);

        // ---- 3x3 spatial conv for the three kd planes over 16 channels ----
        float a0 = 0.f, a1 = 0.f, a2 = 0.f;
        const int wbase = half * 108;   // float4 units: half*9*3*4
#pragma unroll
        for (int k = 0; k < 9; k++) {
            const int off = (k / 3) * HALO + (k % 3);    // compile-time per unrolled k
#pragma unroll
            for (int c4 = 0; c4 < 4; c4++) {
                float4 v  = var_l[convbase + off * VSTR4 + c4];
                float4 w0 = w2_4[wbase + k * 12 + 0 * 4 + c4];
                float4 w1 = w2_4[wbase + k * 12 + 1 * 4 + c4];
                float4 w2v = w2_4[wbase + k * 12 + 2 * 4 + c4];
                a0 = fmaf(v.x, w0.x, a0); a0 = fmaf(v.y, w0.y, a0);
                a0 = fmaf(v.z, w0.z, a0); a0 = fmaf(v.w, w0.w, a0);
                a1 = fmaf(v.x, w1.x, a1); a1 = fmaf(v.y, w1.y, a1);
                a1 = fmaf(v.z, w1.z, a1); a1 = fmaf(v.w, w1.w, a1);
                a2 = fmaf(v.x, w2v.x, a2); a2 = fmaf(v.y, w2v.y, a2);
                a2 = fmaf(v.z, w2v.z, a2); a2 = fmaf(v.w, w2v.w, a2);
            }
        }
        // cost(d) = A0(d-1) + A1(d) + A2(d+1)
        int r;
        r = dp + 1 - d0; if (r >= 0 && r < DCHUNK) cost[r] += a0;
        r = dp - d0;     if (r >= 0 && r < DCHUNK) cost[r] += a1;
        r = dp - 1 - d0; if (r >= 0 && r < DCHUNK) cost[r] += a2;
        __syncthreads();
    }

    float* outv = half ? costB : costA;
    const int h = tileY * TS + ty, w = tileX * TS + tx;
#pragma unroll
    for (int i = 0; i < DCHUNK; i++)
        outv[(d0 + i) * HWc + h * Wc + w] = cost[i];
}

// ---------------- kernel 3: softmax over depth + regression ----------------
__global__ void k_softmax(const float* __restrict__ costA, const float* __restrict__ costB,
                          const float* __restrict__ dvals, const float* __restrict__ breg,
                          float* __restrict__ out)
{
    const int px = blockIdx.x * 256 + threadIdx.x;
    if (px >= HWc) return;
    const float bias = breg[0];
    float c[Dc];
    float m = -1e30f;
#pragma unroll
    for (int d = 0; d < Dc; d++) {
        c[d] = costA[d * HWc + px] + costB[d * HWc + px] + bias;
        m = fmaxf(m, c[d]);
    }
    float se = 0.f, sed = 0.f, me = 0.f;
#pragma unroll
    for (int d = 0; d < Dc; d++) {
        float e = __expf(c[d] - m);
        se += e;
        sed = fmaf(e, dvals[d], sed);
        me = fmaxf(me, e);
    }
    float inv = 1.f / se;
    out[px]       = sed * inv;   // depth
    out[HWc + px] = me * inv;    // photometric confidence
}

extern "C" void kernel_launch(void* const* d_in, const int* in_sizes, int n_in,
                              void* d_out, int out_size, void* d_ws, size_t ws_size,
                              hipStream_t stream) {
    const float* f0    = (const float*)d_in[0];
    const float* f1    = (const float*)d_in[1];
    const float* f2    = (const float*)d_in[2];
    const float* proj  = (const float*)d_in[3];
    const float* dvals = (const float*)d_in[4];
    const float* wreg  = (const float*)d_in[5];
    const float* breg  = (const float*)d_in[6];

    float* ws      = (float*)d_ws;
    float* wsproj  = ws;                    // 24 floats (pad to 32)
    float* w2      = ws + 32;               // 864 floats
    float* fT0     = ws + 896;              // 655360 floats each
    float* fT1     = fT0 + (size_t)HWc * Cc;
    float* fT2     = fT1 + (size_t)HWc * Cc;
    float* costA   = fT2 + (size_t)HWc * Cc;   // Dc*HWc floats
    float* costB   = costA + (size_t)Dc * HWc;

    k_proj<<<1, 64, 0, stream>>>(proj, wreg, wsproj, w2);
    k_transpose<<<dim3(HWc / 256, 3), 256, 0, stream>>>(f0, f1, f2, fT0, fT1, fT2);

    dim3 grid(Wc / TS, Hc / TS, NCHUNK * 2);   // 10 x 8 x 12 = 960 blocks
    k_cost<<<grid, 256, 0, stream>>>(fT0, fT1, fT2, dvals, (const float4*)w2,
                                     wsproj, costA, costB);

    k_softmax<<<HWc / 256, 256, 0, stream>>>(costA, costB, dvals, breg, (float*)d_out);
}